// Round 4
// baseline (200.565 us; speedup 1.0000x reference)
//
#include <hip/hip_runtime.h>
#include <hip/hip_bf16.h>

// L=4096, N=B=64. CH=8 -> CN=512 chunks (2 WG/CU on 256 CUs).
// Scan hierarchy: 512 chunks = 64 groups x 8 = 8 supers x 8 groups x 8.
// P stored ROW-MAJOR packed (hi<<16)|lo bf16 u32; V stored fp32 transposed.
// This round: A/P operands are loaded straight from global into per-wave
// register fragments (no Aop LDS, no staging barrier); the recurrent state
// lives in DOUBLE-BUFFERED LDS -> exactly ONE barrier per step.
#define TL 4096
#define NB 64
#define CH 8
#define CN 512
#define AS 72          // LDS row stride (bf16): 144 B (odd 16B groups -> conflict-free b128)

typedef __attribute__((ext_vector_type(8))) short short8;
typedef __attribute__((ext_vector_type(4))) short short4v;
typedef __attribute__((ext_vector_type(4))) float floatx4;
typedef __attribute__((ext_vector_type(4))) unsigned int uint4v;

__device__ inline floatx4 mfma_bf16(short8 a, short8 b, floatx4 c) {
    return __builtin_amdgcn_mfma_f32_16x16x32_bf16(a, b, c, 0, 0, 0);
}
__device__ inline short bf16_rne(float x) {
    union { __hip_bfloat16 b; unsigned short s; } u;
    u.b = __float2bfloat16(x);
    return (short)u.s;
}
// fp32 -> (hi, lo) bf16 pair. x ~= hi + lo to ~2^-17 rel.
__device__ inline void split_bf16(float x, short& h, short& l) {
    h = bf16_rne(x);
    union { unsigned u; float f; } hv; hv.u = ((unsigned)(unsigned short)h) << 16;
    l = bf16_rne(x - hv.f);
}
// 8 consecutive fp32 (2 float4) -> hi/lo bf16 fragments
__device__ inline void cvt_frag(float4 a, float4 b, short8& H, short8& L) {
    float v[8] = {a.x,a.y,a.z,a.w,b.x,b.y,b.z,b.w};
#pragma unroll
    for (int r = 0; r < 8; ++r) { short hh,ll; split_bf16(v[r],hh,ll); H[r]=hh; L[r]=ll; }
}
// 8 packed u32 (2 uint4) -> hi/lo fragments
__device__ inline void unpack_frag(uint4v a, uint4v b, short8& H, short8& L) {
#pragma unroll
    for (int r = 0; r < 4; ++r) {
        H[r]   = (short)(a[r] >> 16); L[r]   = (short)(a[r] & 0xFFFFu);
        H[4+r] = (short)(b[r] >> 16); L[4+r] = (short)(b[r] & 0xFFFFu);
    }
}

// ---------------------------------------------------------------------------
// Phase 1: per chunk c, S <- A[t]*S (S0=I), V <- A[t]*V + b_t (x) i_t.
// Step 0 direct (S=A[t0] exact). A-frags from global; state dbuf in LDS.
// Emits P32[c] = S row-major packed hi|lo, VT[c] = V^T fp32.
// ---------------------------------------------------------------------------
__global__ __launch_bounds__(256, 2)
void hippo_phase1(const float* __restrict__ inp, const float* __restrict__ Ag,
                  const float* __restrict__ Bst,
                  unsigned* __restrict__ P32, float* __restrict__ VT)
{
    __shared__ short SBh[2][NB][AS], SBl[2][NB][AS];
    __shared__ short VBh[2][NB][AS], VBl[2][NB][AS];

    const int tid = threadIdx.x;
    const int c = blockIdx.x, t0 = c * CH;
    const int w = tid >> 6, lane = tid & 63;
    const int quad = lane >> 4, l15 = lane & 15;
    const int wm = w >> 1, wb = w & 1;
    const int mr0 = 32*wm, br0 = 32*wb;
    const int row0 = mr0 + l15;        // A-frag row (+16*mi)
    const int wr0  = mr0 + 4*quad;     // acc row base (+16*mi)
    const int col0 = br0 + l15;        // acc/state col (+16*ni)

    // issue raw A[t0+1] frag loads + b/i(t0, t0+1)
    float4 rA[2][2][2];
#pragma unroll
    for (int mi = 0; mi < 2; ++mi)
#pragma unroll
    for (int kc = 0; kc < 2; ++kc) {
        const float* p = Ag + (size_t)(t0+1)*4096 + (row0 + 16*mi)*64 + 32*kc + 8*quad;
        rA[mi][kc][0] = *(const float4*)p;
        rA[mi][kc][1] = *(const float4*)(p + 4);
    }
    float4 bcur[2], bnxt[2]; float icur[2], inxt[2];
#pragma unroll
    for (int mi = 0; mi < 2; ++mi) {
        bcur[mi] = *(const float4*)(Bst + (size_t)t0*64 + wr0 + 16*mi);
        bnxt[mi] = *(const float4*)(Bst + (size_t)(t0+1)*64 + wr0 + 16*mi);
    }
    icur[0] = inp[(size_t)t0*64 + col0];
    icur[1] = inp[(size_t)t0*64 + col0 + 16];
    inxt[0] = inp[(size_t)(t0+1)*64 + col0];
    inxt[1] = inp[(size_t)(t0+1)*64 + col0 + 16];

    floatx4 accS[2][2], accV[2][2];
    {   // ---- s=0 direct: S = A[t0] (exact fp32), V = b0 (x) i0 ----
        const float* A0 = Ag + (size_t)t0 * 4096;
        float bc[2][4] = {{bcur[0].x,bcur[0].y,bcur[0].z,bcur[0].w},
                          {bcur[1].x,bcur[1].y,bcur[1].z,bcur[1].w}};
#pragma unroll
        for (int mi = 0; mi < 2; ++mi)
#pragma unroll
        for (int ni = 0; ni < 2; ++ni) {
#pragma unroll
            for (int r = 0; r < 4; ++r) {
                accS[mi][ni][r] = A0[(size_t)(wr0 + 16*mi + r)*64 + col0 + 16*ni];
                accV[mi][ni][r] = bc[mi][r] * icur[ni];
            }
        }
    }
    // convert step-1 A fragments (loads issued above)
    short8 aH[2][2], aL[2][2];
#pragma unroll
    for (int mi = 0; mi < 2; ++mi)
#pragma unroll
    for (int kc = 0; kc < 2; ++kc)
        cvt_frag(rA[mi][kc][0], rA[mi][kc][1], aH[mi][kc], aL[mi][kc]);

    // state s=0 -> buf 0
#pragma unroll
    for (int mi = 0; mi < 2; ++mi)
#pragma unroll
    for (int ni = 0; ni < 2; ++ni) {
        const int cc = col0 + 16*ni, r0 = wr0 + 16*mi;
        short4v h4, l4;
#pragma unroll
        for (int r = 0; r < 4; ++r) { short hh,ll; split_bf16(accS[mi][ni][r],hh,ll); h4[r]=hh; l4[r]=ll; }
        *(short4v*)&SBh[0][cc][r0] = h4; *(short4v*)&SBl[0][cc][r0] = l4;
#pragma unroll
        for (int r = 0; r < 4; ++r) { short hh,ll; split_bf16(accV[mi][ni][r],hh,ll); h4[r]=hh; l4[r]=ll; }
        *(short4v*)&VBh[0][cc][r0] = h4; *(short4v*)&VBl[0][cc][r0] = l4;
    }
    __syncthreads();

    int cur = 0;
    bcur[0]=bnxt[0]; bcur[1]=bnxt[1]; icur[0]=inxt[0]; icur[1]=inxt[1];

    for (int s = 1; s < CH; ++s) {
        if (s + 1 < CH) {       // prefetch A/b/i for s+1
            const int t1 = t0 + s + 1;
#pragma unroll
            for (int mi = 0; mi < 2; ++mi)
#pragma unroll
            for (int kc = 0; kc < 2; ++kc) {
                const float* p = Ag + (size_t)t1*4096 + (row0 + 16*mi)*64 + 32*kc + 8*quad;
                rA[mi][kc][0] = *(const float4*)p;
                rA[mi][kc][1] = *(const float4*)(p + 4);
            }
#pragma unroll
            for (int mi = 0; mi < 2; ++mi)
                bnxt[mi] = *(const float4*)(Bst + (size_t)t1*64 + wr0 + 16*mi);
            inxt[0] = inp[(size_t)t1*64 + col0];
            inxt[1] = inp[(size_t)t1*64 + col0 + 16];
        }
        {
            float bc[2][4] = {{bcur[0].x,bcur[0].y,bcur[0].z,bcur[0].w},
                              {bcur[1].x,bcur[1].y,bcur[1].z,bcur[1].w}};
#pragma unroll
            for (int mi = 0; mi < 2; ++mi)
#pragma unroll
            for (int ni = 0; ni < 2; ++ni)
#pragma unroll
            for (int r = 0; r < 4; ++r) {
                accS[mi][ni][r] = 0.0f;
                accV[mi][ni][r] = bc[mi][r] * icur[ni];
            }
        }
#pragma unroll
        for (int kc = 0; kc < 2; ++kc) {
            const int ko = 32*kc + 8*quad;
#pragma unroll
            for (int ni = 0; ni < 2; ++ni) {
                const int n = col0 + 16*ni;
                short8 sH = *(const short8*)&SBh[cur][n][ko];
                short8 sL = *(const short8*)&SBl[cur][n][ko];
                short8 vH = *(const short8*)&VBh[cur][n][ko];
                short8 vL = *(const short8*)&VBl[cur][n][ko];
                accS[0][ni] = mfma_bf16(aH[0][kc], sH, accS[0][ni]);
                accS[0][ni] = mfma_bf16(aH[0][kc], sL, accS[0][ni]);
                accS[0][ni] = mfma_bf16(aL[0][kc], sH, accS[0][ni]);
                accS[1][ni] = mfma_bf16(aH[1][kc], sH, accS[1][ni]);
                accS[1][ni] = mfma_bf16(aH[1][kc], sL, accS[1][ni]);
                accS[1][ni] = mfma_bf16(aL[1][kc], sH, accS[1][ni]);
                accV[0][ni] = mfma_bf16(aH[0][kc], vH, accV[0][ni]);
                accV[0][ni] = mfma_bf16(aH[0][kc], vL, accV[0][ni]);
                accV[0][ni] = mfma_bf16(aL[0][kc], vH, accV[0][ni]);
                accV[1][ni] = mfma_bf16(aH[1][kc], vH, accV[1][ni]);
                accV[1][ni] = mfma_bf16(aH[1][kc], vL, accV[1][ni]);
                accV[1][ni] = mfma_bf16(aL[1][kc], vH, accV[1][ni]);
            }
        }
        if (s + 1 < CH) {
            // convert next-step A frags (off the state critical path)
#pragma unroll
            for (int mi = 0; mi < 2; ++mi)
#pragma unroll
            for (int kc = 0; kc < 2; ++kc)
                cvt_frag(rA[mi][kc][0], rA[mi][kc][1], aH[mi][kc], aL[mi][kc]);
            // state writeback -> buf[cur^1]; single barrier per step
            const int nb = cur ^ 1;
#pragma unroll
            for (int mi = 0; mi < 2; ++mi)
#pragma unroll
            for (int ni = 0; ni < 2; ++ni) {
                const int cc = col0 + 16*ni, r0 = wr0 + 16*mi;
                short4v h4, l4;
#pragma unroll
                for (int r = 0; r < 4; ++r) { short hh,ll; split_bf16(accS[mi][ni][r],hh,ll); h4[r]=hh; l4[r]=ll; }
                *(short4v*)&SBh[nb][cc][r0] = h4; *(short4v*)&SBl[nb][cc][r0] = l4;
#pragma unroll
                for (int r = 0; r < 4; ++r) { short hh,ll; split_bf16(accV[mi][ni][r],hh,ll); h4[r]=hh; l4[r]=ll; }
                *(short4v*)&VBh[nb][cc][r0] = h4; *(short4v*)&VBl[nb][cc][r0] = l4;
            }
            __syncthreads();
        }
        cur ^= 1;
        bcur[0]=bnxt[0]; bcur[1]=bnxt[1]; icur[0]=inxt[0]; icur[1]=inxt[1];
    }

    unsigned* po = P32 + (size_t)c * 4096;
#pragma unroll
    for (int mi = 0; mi < 2; ++mi)
#pragma unroll
    for (int ni = 0; ni < 2; ++ni) {
        const int cc = col0 + 16*ni, r0 = wr0 + 16*mi;
        *(floatx4*)(VT + (size_t)c*4096 + cc*64 + r0) = accV[mi][ni];
#pragma unroll
        for (int r = 0; r < 4; ++r) {
            short hh, ll; split_bf16(accS[mi][ni][r], hh, ll);
            po[(size_t)(r0 + r)*64 + cc] = ((unsigned)(unsigned short)hh << 16) | (unsigned)(unsigned short)ll;
        }
    }
}

// ---------------------------------------------------------------------------
// Sequential in-place scan of 8 elements per block.
// idx = blockIdx.x*bstride + off0 + i*estride.  Slot i <- prefix 0..i.
// Pnew = P_i*Pacc (Aop = P_i from global packed), Vnew = P_i*Vacc + V_i.
// State (Pacc,Vacc) double-buffered in LDS -> one barrier per element.
// ---------------------------------------------------------------------------
__global__ __launch_bounds__(256, 2)
void hippo_seqscan(unsigned* __restrict__ P32, float* __restrict__ VT,
                   int bstride, int off0, int estride)
{
    __shared__ short PBh[2][NB][AS], PBl[2][NB][AS];
    __shared__ short VBh[2][NB][AS], VBl[2][NB][AS];

    const int tid = threadIdx.x;
    const int base = blockIdx.x * bstride + off0;
    const int w = tid >> 6, lane = tid & 63;
    const int quad = lane >> 4, l15 = lane & 15;
    const int wm = w >> 1, wb = w & 1;
    const int mr0 = 32*wm, br0 = 32*wb;
    const int row0 = mr0 + l15;
    const int wr0  = mr0 + 4*quad;
    const int col0 = br0 + l15;

    // stage element 0 -> Bop buf 0 (transpose scatter for P, row copy for V)
    {
        const unsigned* p0 = P32 + (size_t)base * 4096;
        const float*    v0 = VT  + (size_t)base * 4096;
#pragma unroll
        for (int q = 0; q < 4; ++q) {
            int f = tid + q * 256;
            int k = f & 63, m0 = (f >> 6) * 4;
            uint4v pk = *(const uint4v*)(p0 + k * 64 + m0);
#pragma unroll
            for (int r = 0; r < 4; ++r) {
                PBh[0][m0 + r][k] = (short)(pk[r] >> 16);
                PBl[0][m0 + r][k] = (short)(pk[r] & 0xFFFFu);
            }
        }
#pragma unroll
        for (int q = 0; q < 4; ++q) {
            int f = tid + q * 256;
            int n = f >> 4, k0 = (f & 15) * 4;
            float4 vv = *(const float4*)(v0 + n * 64 + k0);
            float va[4] = {vv.x, vv.y, vv.z, vv.w};
            short4v vh4, vl4;
#pragma unroll
            for (int r = 0; r < 4; ++r) { short hh, ll; split_bf16(va[r], hh, ll); vh4[r]=hh; vl4[r]=ll; }
            *(short4v*)&VBh[0][n][k0] = vh4; *(short4v*)&VBl[0][n][k0] = vl4;
        }
    }
    // prefetch element 1 (raw packed P frags + C-layout V)
    uint4v rP[2][2][2]; float4 preV[2][2];
    {
        const unsigned* pc = P32 + (size_t)(base + estride) * 4096;
        const float*    vc = VT  + (size_t)(base + estride) * 4096;
#pragma unroll
        for (int mi = 0; mi < 2; ++mi)
#pragma unroll
        for (int kc = 0; kc < 2; ++kc) {
            const unsigned* p = pc + (size_t)(row0 + 16*mi)*64 + 32*kc + 8*quad;
            rP[mi][kc][0] = *(const uint4v*)p;
            rP[mi][kc][1] = *(const uint4v*)(p + 4);
        }
#pragma unroll
        for (int mi = 0; mi < 2; ++mi)
#pragma unroll
        for (int ni = 0; ni < 2; ++ni)
            preV[mi][ni] = *(const float4*)(vc + (size_t)(col0 + 16*ni)*64 + wr0 + 16*mi);
    }
    __syncthreads();

    short8 aH[2][2], aL[2][2];
#pragma unroll
    for (int mi = 0; mi < 2; ++mi)
#pragma unroll
    for (int kc = 0; kc < 2; ++kc)
        unpack_frag(rP[mi][kc][0], rP[mi][kc][1], aH[mi][kc], aL[mi][kc]);

    int cur = 0;
    for (int i = 1; i < 8; ++i) {
        const int idx = base + i * estride;
        floatx4 accP[2][2], accV[2][2];
#pragma unroll
        for (int mi = 0; mi < 2; ++mi)
#pragma unroll
        for (int ni = 0; ni < 2; ++ni) {
            accV[mi][ni][0] = preV[mi][ni].x; accV[mi][ni][1] = preV[mi][ni].y;
            accV[mi][ni][2] = preV[mi][ni].z; accV[mi][ni][3] = preV[mi][ni].w;
            accP[mi][ni][0]=accP[mi][ni][1]=accP[mi][ni][2]=accP[mi][ni][3]=0.0f;
        }
        if (i + 1 < 8) {
            const unsigned* pc = P32 + (size_t)(base + (i+1) * estride) * 4096;
            const float*    vc = VT  + (size_t)(base + (i+1) * estride) * 4096;
#pragma unroll
            for (int mi = 0; mi < 2; ++mi)
#pragma unroll
            for (int kc = 0; kc < 2; ++kc) {
                const unsigned* p = pc + (size_t)(row0 + 16*mi)*64 + 32*kc + 8*quad;
                rP[mi][kc][0] = *(const uint4v*)p;
                rP[mi][kc][1] = *(const uint4v*)(p + 4);
            }
#pragma unroll
            for (int mi = 0; mi < 2; ++mi)
#pragma unroll
            for (int ni = 0; ni < 2; ++ni)
                preV[mi][ni] = *(const float4*)(vc + (size_t)(col0 + 16*ni)*64 + wr0 + 16*mi);
        }
#pragma unroll
        for (int kc = 0; kc < 2; ++kc) {
            const int ko = 32*kc + 8*quad;
#pragma unroll
            for (int ni = 0; ni < 2; ++ni) {
                const int n = col0 + 16*ni;
                short8 pH = *(const short8*)&PBh[cur][n][ko];
                short8 pL = *(const short8*)&PBl[cur][n][ko];
                short8 vH = *(const short8*)&VBh[cur][n][ko];
                short8 vL = *(const short8*)&VBl[cur][n][ko];
                accP[0][ni] = mfma_bf16(aH[0][kc], pH, accP[0][ni]);
                accP[0][ni] = mfma_bf16(aH[0][kc], pL, accP[0][ni]);
                accP[0][ni] = mfma_bf16(aL[0][kc], pH, accP[0][ni]);
                accP[1][ni] = mfma_bf16(aH[1][kc], pH, accP[1][ni]);
                accP[1][ni] = mfma_bf16(aH[1][kc], pL, accP[1][ni]);
                accP[1][ni] = mfma_bf16(aL[1][kc], pH, accP[1][ni]);
                accV[0][ni] = mfma_bf16(aH[0][kc], vH, accV[0][ni]);
                accV[0][ni] = mfma_bf16(aH[0][kc], vL, accV[0][ni]);
                accV[0][ni] = mfma_bf16(aL[0][kc], vH, accV[0][ni]);
                accV[1][ni] = mfma_bf16(aH[1][kc], vH, accV[1][ni]);
                accV[1][ni] = mfma_bf16(aH[1][kc], vL, accV[1][ni]);
                accV[1][ni] = mfma_bf16(aL[1][kc], vH, accV[1][ni]);
            }
        }
        if (i + 1 < 8) {
#pragma unroll
            for (int mi = 0; mi < 2; ++mi)
#pragma unroll
            for (int kc = 0; kc < 2; ++kc)
                unpack_frag(rP[mi][kc][0], rP[mi][kc][1], aH[mi][kc], aL[mi][kc]);
        }
        unsigned* po = P32 + (size_t)idx * 4096;
        const int nb = cur ^ 1;
#pragma unroll
        for (int mi = 0; mi < 2; ++mi)
#pragma unroll
        for (int ni = 0; ni < 2; ++ni) {
            const int cc = col0 + 16*ni, r0 = wr0 + 16*mi;
            *(floatx4*)(VT + (size_t)idx*4096 + cc*64 + r0) = accV[mi][ni];
            short4v h4, l4;
#pragma unroll
            for (int r = 0; r < 4; ++r) {
                short hh, ll; split_bf16(accP[mi][ni][r], hh, ll);
                po[(size_t)(r0+r)*64 + cc] = ((unsigned)(unsigned short)hh << 16) | (unsigned)(unsigned short)ll;
                h4[r]=hh; l4[r]=ll;
            }
            if (i + 1 < 8) {
                *(short4v*)&PBh[nb][cc][r0] = h4; *(short4v*)&PBl[nb][cc][r0] = l4;
                short4v vh4, vl4;
#pragma unroll
                for (int r = 0; r < 4; ++r) { short hh,ll; split_bf16(accV[mi][ni][r],hh,ll); vh4[r]=hh; vl4[r]=ll; }
                *(short4v*)&VBh[nb][cc][r0] = vh4; *(short4v*)&VBl[nb][cc][r0] = vl4;
            }
        }
        if (i + 1 < 8) __syncthreads();
        cur ^= 1;
    }
}

// ---------------------------------------------------------------------------
// S3: 1 block. E_0 = 0; E_{s+1} = P[64s+63]*E_s + V[64s+63].
// P-frags from global packed; E dbuf in LDS; one barrier per iter.
// Stores E_{s+1} fp32 into dead P32 slot idx=64s+63, layout [b][n].
// ---------------------------------------------------------------------------
__global__ __launch_bounds__(256, 2)
void hippo_s3(unsigned* __restrict__ P32, const float* __restrict__ VT)
{
    __shared__ short EBh[2][NB][AS], EBl[2][NB][AS];
    const int tid = threadIdx.x;
    const int w = tid >> 6, lane = tid & 63, quad = lane >> 4, l15 = lane & 15;
    const int wm = w >> 1, wb = w & 1;
    const int mr0 = 32*wm, br0 = 32*wb;
    const int row0 = mr0 + l15;
    const int wr0  = mr0 + 4*quad;
    const int col0 = br0 + l15;

#pragma unroll
    for (int q = 0; q < 16; ++q) {
        int f = tid + q * 256; EBh[0][f >> 6][f & 63] = 0; EBl[0][f >> 6][f & 63] = 0;
    }
    uint4v rP[2][2][2]; float4 preV[2][2];
    {
        const unsigned* pc = P32 + (size_t)63 * 4096;
        const float*    vc = VT  + (size_t)63 * 4096;
#pragma unroll
        for (int mi = 0; mi < 2; ++mi)
#pragma unroll
        for (int kc = 0; kc < 2; ++kc) {
            const unsigned* p = pc + (size_t)(row0 + 16*mi)*64 + 32*kc + 8*quad;
            rP[mi][kc][0] = *(const uint4v*)p;
            rP[mi][kc][1] = *(const uint4v*)(p + 4);
        }
#pragma unroll
        for (int mi = 0; mi < 2; ++mi)
#pragma unroll
        for (int ni = 0; ni < 2; ++ni)
            preV[mi][ni] = *(const float4*)(vc + (size_t)(col0 + 16*ni)*64 + wr0 + 16*mi);
    }
    __syncthreads();

    short8 aH[2][2], aL[2][2];
#pragma unroll
    for (int mi = 0; mi < 2; ++mi)
#pragma unroll
    for (int kc = 0; kc < 2; ++kc)
        unpack_frag(rP[mi][kc][0], rP[mi][kc][1], aH[mi][kc], aL[mi][kc]);

    int cur = 0;
    for (int s = 0; s < 7; ++s) {
        const int idx = 64 * s + 63;
        floatx4 acc[2][2];
#pragma unroll
        for (int mi = 0; mi < 2; ++mi)
#pragma unroll
        for (int ni = 0; ni < 2; ++ni) {
            acc[mi][ni][0] = preV[mi][ni].x; acc[mi][ni][1] = preV[mi][ni].y;
            acc[mi][ni][2] = preV[mi][ni].z; acc[mi][ni][3] = preV[mi][ni].w;
        }
        if (s + 1 < 7) {
            const int idx2 = 64 * (s + 1) + 63;
            const unsigned* pc = P32 + (size_t)idx2 * 4096;
            const float*    vc = VT  + (size_t)idx2 * 4096;
#pragma unroll
            for (int mi = 0; mi < 2; ++mi)
#pragma unroll
            for (int kc = 0; kc < 2; ++kc) {
                const unsigned* p = pc + (size_t)(row0 + 16*mi)*64 + 32*kc + 8*quad;
                rP[mi][kc][0] = *(const uint4v*)p;
                rP[mi][kc][1] = *(const uint4v*)(p + 4);
            }
#pragma unroll
            for (int mi = 0; mi < 2; ++mi)
#pragma unroll
            for (int ni = 0; ni < 2; ++ni)
                preV[mi][ni] = *(const float4*)(vc + (size_t)(col0 + 16*ni)*64 + wr0 + 16*mi);
        }
#pragma unroll
        for (int kc = 0; kc < 2; ++kc) {
            const int ko = 32*kc + 8*quad;
#pragma unroll
            for (int ni = 0; ni < 2; ++ni) {
                const int n = col0 + 16*ni;
                short8 eH = *(const short8*)&EBh[cur][n][ko];
                short8 eL = *(const short8*)&EBl[cur][n][ko];
                acc[0][ni] = mfma_bf16(aH[0][kc], eH, acc[0][ni]);
                acc[0][ni] = mfma_bf16(aH[0][kc], eL, acc[0][ni]);
                acc[0][ni] = mfma_bf16(aL[0][kc], eH, acc[0][ni]);
                acc[1][ni] = mfma_bf16(aH[1][kc], eH, acc[1][ni]);
                acc[1][ni] = mfma_bf16(aH[1][kc], eL, acc[1][ni]);
                acc[1][ni] = mfma_bf16(aL[1][kc], eH, acc[1][ni]);
            }
        }
        if (s + 1 < 7) {
#pragma unroll
            for (int mi = 0; mi < 2; ++mi)
#pragma unroll
            for (int kc = 0; kc < 2; ++kc)
                unpack_frag(rP[mi][kc][0], rP[mi][kc][1], aH[mi][kc], aL[mi][kc]);
        }
        float* eo = (float*)(P32 + (size_t)idx * 4096);
        const int nb = cur ^ 1;
#pragma unroll
        for (int mi = 0; mi < 2; ++mi)
#pragma unroll
        for (int ni = 0; ni < 2; ++ni) {
            const int cc = col0 + 16*ni, r0 = wr0 + 16*mi;
            *(floatx4*)(eo + cc*64 + r0) = acc[mi][ni];
            if (s + 1 < 7) {
                short4v h4, l4;
#pragma unroll
                for (int r = 0; r < 4; ++r) { short hh,ll; split_bf16(acc[mi][ni][r],hh,ll); h4[r]=hh; l4[r]=ll; }
                *(short4v*)&EBh[nb][cc][r0] = h4; *(short4v*)&EBl[nb][cc][r0] = l4;
            }
        }
        if (s + 1 < 7) __syncthreads();
        cur ^= 1;
    }
}

// ---------------------------------------------------------------------------
// Phase 3: entering state = (super E) combined with stored prefixes, then
// x <- A[t] x + u_t for 8 local steps.  A/P frags from global; X dbuf in LDS.
// ---------------------------------------------------------------------------
__global__ __launch_bounds__(256, 2)
void hippo_phase3(const float* __restrict__ inp, const float* __restrict__ Ag,
                  const float* __restrict__ Bst, const unsigned* __restrict__ P32,
                  const float* __restrict__ VT, float* __restrict__ out)
{
    __shared__ short XBh[2][NB][AS], XBl[2][NB][AS];

    const int tid = threadIdx.x, c = blockIdx.x, t0 = c * CH;
    const int w = tid >> 6, lane = tid & 63, quad = lane >> 4, l15 = lane & 15;
    const int wm = w >> 1, wb = w & 1;
    const int mr0 = 32*wm, br0 = 32*wb;
    const int row0 = mr0 + l15;
    const int wr0  = mr0 + 4*quad;
    const int col0 = br0 + l15;
    const int sup = c >> 6, g = c >> 3, gi = g & 7, j = c & 7;

    // issue raw A[t0] frag loads + b/i(t0) early (hide HBM under combines)
    float4 rA[2][2][2];
#pragma unroll
    for (int mi = 0; mi < 2; ++mi)
#pragma unroll
    for (int kc = 0; kc < 2; ++kc) {
        const float* p = Ag + (size_t)t0*4096 + (row0 + 16*mi)*64 + 32*kc + 8*quad;
        rA[mi][kc][0] = *(const float4*)p;
        rA[mi][kc][1] = *(const float4*)(p + 4);
    }
    float4 bcur[2], bnxt[2]; float icur[2], inxt[2];
#pragma unroll
    for (int mi = 0; mi < 2; ++mi)
        bcur[mi] = *(const float4*)(Bst + (size_t)t0*64 + wr0 + 16*mi);
    icur[0] = inp[(size_t)t0*64 + col0];
    icur[1] = inp[(size_t)t0*64 + col0 + 16];

    // ---- entering super state -> buf 0 ----
    if (sup == 0) {
#pragma unroll
        for (int q = 0; q < 16; ++q) { int f = tid + q*256; XBh[0][f>>6][f&63] = 0; XBl[0][f>>6][f&63] = 0; }
    } else {
        const float* e = (const float*)(P32 + (size_t)(64*(sup-1) + 63) * 4096);  // E_sup [b][n]
#pragma unroll
        for (int q = 0; q < 4; ++q) {
            int f = tid + q*256; int b = f>>4, k0 = (f&15)*4;
            float4 v = *(const float4*)(e + b*64 + k0);
            float va[4] = {v.x,v.y,v.z,v.w};
            short4v h4, l4;
#pragma unroll
            for (int r=0;r<4;++r){short hh,ll;split_bf16(va[r],hh,ll);h4[r]=hh;l4[r]=ll;}
            *(short4v*)&XBh[0][b][k0] = h4; *(short4v*)&XBl[0][b][k0] = l4;
        }
    }
    __syncthreads();
    int cur = 0;

    // ---- apply stored prefixes: X <- P[idx]*X + V[idx] ----
    auto combine = [&](int idx) {
        uint4v rP[2][2][2];
        const unsigned* pc = P32 + (size_t)idx * 4096;
        const float*    vc = VT  + (size_t)idx * 4096;
#pragma unroll
        for (int mi = 0; mi < 2; ++mi)
#pragma unroll
        for (int kc = 0; kc < 2; ++kc) {
            const unsigned* p = pc + (size_t)(row0 + 16*mi)*64 + 32*kc + 8*quad;
            rP[mi][kc][0] = *(const uint4v*)p;
            rP[mi][kc][1] = *(const uint4v*)(p + 4);
        }
        floatx4 acc[2][2];
#pragma unroll
        for (int mi = 0; mi < 2; ++mi)
#pragma unroll
        for (int ni = 0; ni < 2; ++ni) {
            float4 vv = *(const float4*)(vc + (size_t)(col0 + 16*ni)*64 + wr0 + 16*mi);
            acc[mi][ni][0]=vv.x; acc[mi][ni][1]=vv.y; acc[mi][ni][2]=vv.z; acc[mi][ni][3]=vv.w;
        }
        short8 cH[2][2], cL[2][2];
#pragma unroll
        for (int mi = 0; mi < 2; ++mi)
#pragma unroll
        for (int kc = 0; kc < 2; ++kc)
            unpack_frag(rP[mi][kc][0], rP[mi][kc][1], cH[mi][kc], cL[mi][kc]);
#pragma unroll
        for (int kc = 0; kc < 2; ++kc) {
            const int ko = 32*kc + 8*quad;
#pragma unroll
            for (int ni = 0; ni < 2; ++ni) {
                const int n = col0 + 16*ni;
                short8 xH = *(const short8*)&XBh[cur][n][ko];
                short8 xL = *(const short8*)&XBl[cur][n][ko];
                acc[0][ni] = mfma_bf16(cH[0][kc], xH, acc[0][ni]);
                acc[0][ni] = mfma_bf16(cH[0][kc], xL, acc[0][ni]);
                acc[0][ni] = mfma_bf16(cL[0][kc], xH, acc[0][ni]);
                acc[1][ni] = mfma_bf16(cH[1][kc], xH, acc[1][ni]);
                acc[1][ni] = mfma_bf16(cH[1][kc], xL, acc[1][ni]);
                acc[1][ni] = mfma_bf16(cL[1][kc], xH, acc[1][ni]);
            }
        }
        const int nb = cur ^ 1;
#pragma unroll
        for (int mi = 0; mi < 2; ++mi)
#pragma unroll
        for (int ni = 0; ni < 2; ++ni) {
            const int cc = col0 + 16*ni, r0 = wr0 + 16*mi;
            short4v h4, l4;
#pragma unroll
            for (int r=0;r<4;++r){short hh,ll;split_bf16(acc[mi][ni][r],hh,ll);h4[r]=hh;l4[r]=ll;}
            *(short4v*)&XBh[nb][cc][r0] = h4; *(short4v*)&XBl[nb][cc][r0] = l4;
        }
        __syncthreads();
        cur ^= 1;
    };
    if (gi) combine(8*g - 1);   // in-super group prefix (S2 output)
    if (j)  combine(c - 1);     // in-group chunk prefix (S1 output)

    // convert A[t0] frags (loads issued at kernel start)
    short8 aH[2][2], aL[2][2];
#pragma unroll
    for (int mi = 0; mi < 2; ++mi)
#pragma unroll
    for (int kc = 0; kc < 2; ++kc)
        cvt_frag(rA[mi][kc][0], rA[mi][kc][1], aH[mi][kc], aL[mi][kc]);

    // ---- 8 local time steps ----
    floatx4 acc[2][2];
    for (int s = 0; s < CH; ++s) {
        const int t = t0 + s;
        if (s + 1 < CH) {
            const int t1 = t + 1;
#pragma unroll
            for (int mi = 0; mi < 2; ++mi)
#pragma unroll
            for (int kc = 0; kc < 2; ++kc) {
                const float* p = Ag + (size_t)t1*4096 + (row0 + 16*mi)*64 + 32*kc + 8*quad;
                rA[mi][kc][0] = *(const float4*)p;
                rA[mi][kc][1] = *(const float4*)(p + 4);
            }
#pragma unroll
            for (int mi = 0; mi < 2; ++mi)
                bnxt[mi] = *(const float4*)(Bst + (size_t)t1*64 + wr0 + 16*mi);
            inxt[0] = inp[(size_t)t1*64 + col0];
            inxt[1] = inp[(size_t)t1*64 + col0 + 16];
        }
        {
            float bc[2][4] = {{bcur[0].x,bcur[0].y,bcur[0].z,bcur[0].w},
                              {bcur[1].x,bcur[1].y,bcur[1].z,bcur[1].w}};
#pragma unroll
            for (int mi=0;mi<2;++mi)
#pragma unroll
            for (int ni=0;ni<2;++ni)
#pragma unroll
            for (int r=0;r<4;++r) acc[mi][ni][r] = bc[mi][r] * icur[ni];
        }
#pragma unroll
        for (int kc = 0; kc < 2; ++kc) {
            const int ko = 32*kc + 8*quad;
#pragma unroll
            for (int ni = 0; ni < 2; ++ni) {
                const int n = col0 + 16*ni;
                short8 xH = *(const short8*)&XBh[cur][n][ko];
                short8 xL = *(const short8*)&XBl[cur][n][ko];
                acc[0][ni] = mfma_bf16(aH[0][kc], xH, acc[0][ni]);
                acc[0][ni] = mfma_bf16(aH[0][kc], xL, acc[0][ni]);
                acc[0][ni] = mfma_bf16(aL[0][kc], xH, acc[0][ni]);
                acc[1][ni] = mfma_bf16(aH[1][kc], xH, acc[1][ni]);
                acc[1][ni] = mfma_bf16(aH[1][kc], xL, acc[1][ni]);
                acc[1][ni] = mfma_bf16(aL[1][kc], xH, acc[1][ni]);
            }
        }
        if (s + 1 < CH) {
#pragma unroll
            for (int mi = 0; mi < 2; ++mi)
#pragma unroll
            for (int kc = 0; kc < 2; ++kc)
                cvt_frag(rA[mi][kc][0], rA[mi][kc][1], aH[mi][kc], aL[mi][kc]);
        }
        const int nb = cur ^ 1;
#pragma unroll
        for (int mi = 0; mi < 2; ++mi)
#pragma unroll
        for (int ni = 0; ni < 2; ++ni) {
            const int cc = col0 + 16*ni, r0 = wr0 + 16*mi;
            *(floatx4*)(out + (size_t)t*4096 + cc*64 + r0) = acc[mi][ni];   // out[t][b][n0..3]
            if (s + 1 < CH) {
                short4v h4, l4;
#pragma unroll
                for (int r=0;r<4;++r){short hh,ll;split_bf16(acc[mi][ni][r],hh,ll);h4[r]=hh;l4[r]=ll;}
                *(short4v*)&XBh[nb][cc][r0] = h4; *(short4v*)&XBl[nb][cc][r0] = l4;
            }
        }
        if (s + 1 < CH) __syncthreads();
        cur ^= 1;
        bcur[0]=bnxt[0]; bcur[1]=bnxt[1]; icur[0]=inxt[0]; icur[1]=inxt[1];
    }
}

extern "C" void kernel_launch(void* const* d_in, const int* in_sizes, int n_in,
                              void* d_out, int out_size, void* d_ws, size_t ws_size,
                              hipStream_t stream)
{
    const float* inp = (const float*)d_in[0];   // (L, B)
    const float* A   = (const float*)d_in[1];   // (L, N, N)
    const float* Bst = (const float*)d_in[2];   // (L, N)
    float* out = (float*)d_out;                  // (L, B, N)
    float* ws  = (float*)d_ws;                   // 16 MB used

    unsigned* P32 = (unsigned*)ws;               // 8 MB: packed hi|lo, row-major
    float*    VT  = ws + (size_t)CN * 4096;      // 8 MB: fp32, transposed

    hippo_phase1<<<CN, 256, 0, stream>>>(inp, A, Bst, P32, VT);
    hippo_seqscan<<<64, 256, 0, stream>>>(P32, VT, 8, 0, 1);
    hippo_seqscan<<<8, 256, 0, stream>>>(P32, VT, 64, 7, 8);
    hippo_s3<<<1, 256, 0, stream>>>(P32, VT);
    hippo_phase3<<<CN, 256, 0, stream>>>(inp, A, Bst, P32, VT, out);
}

// Round 5
// 183.891 us; speedup vs baseline: 1.0907x; 1.0907x over previous
//
#include <hip/hip_runtime.h>
#include <hip/hip_bf16.h>

// L=4096, N=B=64. CH=8 -> CN=512 chunks (2 WG/CU on 256 CUs).
// Scan hierarchy: 512 chunks = 64 groups x 8 = 8 supers x 8 groups x 8.
// P stored ROW-MAJOR packed (hi<<16)|lo bf16 u32; V stored fp32 transposed.
// Wave tiling 16x64: wave w owns output rows [16w,16w+16) x all 64 cols.
// -> A/P fragment rows (16w+l15) are wave-exclusive: loaded straight from
// global with NO duplication and NO A-LDS staging. Recurrent state lives in
// DOUBLE-BUFFERED LDS -> exactly ONE barrier per step.
#define TL 4096
#define NB 64
#define CH 8
#define CN 512
#define AS 72          // LDS row stride (bf16): 144 B (odd 16B groups -> conflict-free b128)

typedef __attribute__((ext_vector_type(8))) short short8;
typedef __attribute__((ext_vector_type(4))) short short4v;
typedef __attribute__((ext_vector_type(4))) float floatx4;
typedef __attribute__((ext_vector_type(4))) unsigned int uint4v;

__device__ inline floatx4 mfma_bf16(short8 a, short8 b, floatx4 c) {
    return __builtin_amdgcn_mfma_f32_16x16x32_bf16(a, b, c, 0, 0, 0);
}
__device__ inline short bf16_rne(float x) {
    union { __hip_bfloat16 b; unsigned short s; } u;
    u.b = __float2bfloat16(x);
    return (short)u.s;
}
// fp32 -> (hi, lo) bf16 pair. x ~= hi + lo to ~2^-17 rel.
__device__ inline void split_bf16(float x, short& h, short& l) {
    h = bf16_rne(x);
    union { unsigned u; float f; } hv; hv.u = ((unsigned)(unsigned short)h) << 16;
    l = bf16_rne(x - hv.f);
}
// 8 consecutive fp32 (2 float4) -> hi/lo bf16 fragments
__device__ inline void cvt_frag(float4 a, float4 b, short8& H, short8& L) {
    float v[8] = {a.x,a.y,a.z,a.w,b.x,b.y,b.z,b.w};
#pragma unroll
    for (int r = 0; r < 8; ++r) { short hh,ll; split_bf16(v[r],hh,ll); H[r]=hh; L[r]=ll; }
}
// 8 packed u32 (2 uint4) -> hi/lo fragments
__device__ inline void unpack_frag(uint4v a, uint4v b, short8& H, short8& L) {
#pragma unroll
    for (int r = 0; r < 4; ++r) {
        H[r]   = (short)(a[r] >> 16); L[r]   = (short)(a[r] & 0xFFFFu);
        H[4+r] = (short)(b[r] >> 16); L[4+r] = (short)(b[r] & 0xFFFFu);
    }
}

// ---------------------------------------------------------------------------
// Phase 1: per chunk c, S <- A[t]*S (S0=I), V <- A[t]*V + b_t (x) i_t.
// Step 0 direct (S=A[t0] exact). A-frags per-wave from global (no dup);
// state dbuf in LDS, one barrier per step.
// Emits P32[c] = S row-major packed hi|lo, VT[c] = V^T fp32.
// ---------------------------------------------------------------------------
__global__ __launch_bounds__(256, 2)
void hippo_phase1(const float* __restrict__ inp, const float* __restrict__ Ag,
                  const float* __restrict__ Bst,
                  unsigned* __restrict__ P32, float* __restrict__ VT)
{
    __shared__ short SBh[2][NB][AS], SBl[2][NB][AS];
    __shared__ short VBh[2][NB][AS], VBl[2][NB][AS];

    const int tid = threadIdx.x;
    const int c = blockIdx.x, t0 = c * CH;
    const int w = tid >> 6, lane = tid & 63;
    const int quad = lane >> 4, l15 = lane & 15;
    const int arow = 16*w + l15;     // wave-exclusive A row
    const int wr0  = 16*w + 4*quad;  // acc row base

    // issue prefetch of A[t0+1] frags + b/i(t0+1) first (overlap with s=0)
    float4 rA[2][2];
#pragma unroll
    for (int kc = 0; kc < 2; ++kc) {
        const float* p = Ag + (size_t)(t0+1)*4096 + (size_t)arow*64 + 32*kc + 8*quad;
        rA[kc][0] = *(const float4*)p;
        rA[kc][1] = *(const float4*)(p + 4);
    }
    float4 bnxt = *(const float4*)(Bst + (size_t)(t0+1)*64 + wr0);
    float inxt[4];
#pragma unroll
    for (int ni = 0; ni < 4; ++ni) inxt[ni] = inp[(size_t)(t0+1)*64 + l15 + 16*ni];

    // ---- s=0 direct: S = A[t0] (exact fp32), V = b0 (x) i0 ----
    floatx4 accS[4], accV[4];
    {
        const float* A0 = Ag + (size_t)t0 * 4096;
        float4 b0 = *(const float4*)(Bst + (size_t)t0*64 + wr0);
        float bc[4] = {b0.x,b0.y,b0.z,b0.w};
#pragma unroll
        for (int ni = 0; ni < 4; ++ni) {
            const float ii = inp[(size_t)t0*64 + l15 + 16*ni];
#pragma unroll
            for (int r = 0; r < 4; ++r) {
                accS[ni][r] = A0[(size_t)(wr0 + r)*64 + l15 + 16*ni];
                accV[ni][r] = bc[r] * ii;
            }
        }
    }
    // state s=0 -> buf 0
#pragma unroll
    for (int ni = 0; ni < 4; ++ni) {
        const int cc = l15 + 16*ni;
        short4v h4, l4;
#pragma unroll
        for (int r = 0; r < 4; ++r) { short hh,ll; split_bf16(accS[ni][r],hh,ll); h4[r]=hh; l4[r]=ll; }
        *(short4v*)&SBh[0][cc][wr0] = h4; *(short4v*)&SBl[0][cc][wr0] = l4;
#pragma unroll
        for (int r = 0; r < 4; ++r) { short hh,ll; split_bf16(accV[ni][r],hh,ll); h4[r]=hh; l4[r]=ll; }
        *(short4v*)&VBh[0][cc][wr0] = h4; *(short4v*)&VBl[0][cc][wr0] = l4;
    }
    __syncthreads();

    short8 aH[2], aL[2];
#pragma unroll
    for (int kc = 0; kc < 2; ++kc) cvt_frag(rA[kc][0], rA[kc][1], aH[kc], aL[kc]);

    int cur = 0;
    float4 bcur = bnxt;
    float icur[4];
#pragma unroll
    for (int ni = 0; ni < 4; ++ni) icur[ni] = inxt[ni];

    for (int s = 1; s < CH; ++s) {
        if (s + 1 < CH) {   // prefetch A/b/i for s+1
            const int t1 = t0 + s + 1;
#pragma unroll
            for (int kc = 0; kc < 2; ++kc) {
                const float* p = Ag + (size_t)t1*4096 + (size_t)arow*64 + 32*kc + 8*quad;
                rA[kc][0] = *(const float4*)p;
                rA[kc][1] = *(const float4*)(p + 4);
            }
            bnxt = *(const float4*)(Bst + (size_t)t1*64 + wr0);
#pragma unroll
            for (int ni = 0; ni < 4; ++ni) inxt[ni] = inp[(size_t)t1*64 + l15 + 16*ni];
        }
        {
            float bc[4] = {bcur.x,bcur.y,bcur.z,bcur.w};
#pragma unroll
            for (int ni = 0; ni < 4; ++ni)
#pragma unroll
            for (int r = 0; r < 4; ++r) {
                accS[ni][r] = 0.0f;
                accV[ni][r] = bc[r] * icur[ni];
            }
        }
#pragma unroll
        for (int kc = 0; kc < 2; ++kc) {
            const int ko = 32*kc + 8*quad;
#pragma unroll
            for (int ni = 0; ni < 4; ++ni) {
                const int n = l15 + 16*ni;
                short8 sH = *(const short8*)&SBh[cur][n][ko];
                short8 sL = *(const short8*)&SBl[cur][n][ko];
                short8 vH = *(const short8*)&VBh[cur][n][ko];
                short8 vL = *(const short8*)&VBl[cur][n][ko];
                accS[ni] = mfma_bf16(aH[kc], sH, accS[ni]);
                accS[ni] = mfma_bf16(aH[kc], sL, accS[ni]);
                accS[ni] = mfma_bf16(aL[kc], sH, accS[ni]);
                accV[ni] = mfma_bf16(aH[kc], vH, accV[ni]);
                accV[ni] = mfma_bf16(aH[kc], vL, accV[ni]);
                accV[ni] = mfma_bf16(aL[kc], vH, accV[ni]);
            }
        }
        if (s + 1 < CH) {
#pragma unroll
            for (int kc = 0; kc < 2; ++kc) cvt_frag(rA[kc][0], rA[kc][1], aH[kc], aL[kc]);
            const int nb = cur ^ 1;
#pragma unroll
            for (int ni = 0; ni < 4; ++ni) {
                const int cc = l15 + 16*ni;
                short4v h4, l4;
#pragma unroll
                for (int r = 0; r < 4; ++r) { short hh,ll; split_bf16(accS[ni][r],hh,ll); h4[r]=hh; l4[r]=ll; }
                *(short4v*)&SBh[nb][cc][wr0] = h4; *(short4v*)&SBl[nb][cc][wr0] = l4;
#pragma unroll
                for (int r = 0; r < 4; ++r) { short hh,ll; split_bf16(accV[ni][r],hh,ll); h4[r]=hh; l4[r]=ll; }
                *(short4v*)&VBh[nb][cc][wr0] = h4; *(short4v*)&VBl[nb][cc][wr0] = l4;
            }
            __syncthreads();
            cur ^= 1;
        }
        bcur = bnxt;
#pragma unroll
        for (int ni = 0; ni < 4; ++ni) icur[ni] = inxt[ni];
    }

    unsigned* po = P32 + (size_t)c * 4096;
#pragma unroll
    for (int ni = 0; ni < 4; ++ni) {
        const int cc = l15 + 16*ni;
        *(floatx4*)(VT + (size_t)c*4096 + cc*64 + wr0) = accV[ni];
#pragma unroll
        for (int r = 0; r < 4; ++r) {
            short hh, ll; split_bf16(accS[ni][r], hh, ll);
            po[(size_t)(wr0 + r)*64 + cc] = ((unsigned)(unsigned short)hh << 16) | (unsigned)(unsigned short)ll;
        }
    }
}

// ---------------------------------------------------------------------------
// Sequential in-place scan of 8 elements per block.
// idx = blockIdx.x*bstride + off0 + i*estride.  Slot i <- prefix 0..i.
// Pnew = P_i*Pacc (Aop = P_i, per-wave global, no dup), Vnew = P_i*Vacc + V_i.
// State (Pacc,Vacc) dbuf in LDS -> one barrier per element.
// ---------------------------------------------------------------------------
__global__ __launch_bounds__(256, 2)
void hippo_seqscan(unsigned* __restrict__ P32, float* __restrict__ VT,
                   int bstride, int off0, int estride)
{
    __shared__ short PBh[2][NB][AS], PBl[2][NB][AS];
    __shared__ short VBh[2][NB][AS], VBl[2][NB][AS];

    const int tid = threadIdx.x;
    const int base = blockIdx.x * bstride + off0;
    const int w = tid >> 6, lane = tid & 63;
    const int quad = lane >> 4, l15 = lane & 15;
    const int arow = 16*w + l15;
    const int wr0  = 16*w + 4*quad;

    // stage element 0 -> buf 0 (transpose scatter for P, row copy for V)
    {
        const unsigned* p0 = P32 + (size_t)base * 4096;
        const float*    v0 = VT  + (size_t)base * 4096;
#pragma unroll
        for (int q = 0; q < 4; ++q) {
            int f = tid + q * 256;
            int k = f & 63, m0 = (f >> 6) * 4;
            uint4v pk = *(const uint4v*)(p0 + k * 64 + m0);
#pragma unroll
            for (int r = 0; r < 4; ++r) {
                PBh[0][m0 + r][k] = (short)(pk[r] >> 16);
                PBl[0][m0 + r][k] = (short)(pk[r] & 0xFFFFu);
            }
        }
#pragma unroll
        for (int q = 0; q < 4; ++q) {
            int f = tid + q * 256;
            int n = f >> 4, k0 = (f & 15) * 4;
            float4 vv = *(const float4*)(v0 + n * 64 + k0);
            float va[4] = {vv.x, vv.y, vv.z, vv.w};
            short4v vh4, vl4;
#pragma unroll
            for (int r = 0; r < 4; ++r) { short hh, ll; split_bf16(va[r], hh, ll); vh4[r]=hh; vl4[r]=ll; }
            *(short4v*)&VBh[0][n][k0] = vh4; *(short4v*)&VBl[0][n][k0] = vl4;
        }
    }
    // prefetch element 1 (wave-exclusive packed P rows + C-layout V)
    uint4v rP[2][2]; float4 preV[4];
    {
        const unsigned* pc = P32 + (size_t)(base + estride) * 4096;
        const float*    vc = VT  + (size_t)(base + estride) * 4096;
#pragma unroll
        for (int kc = 0; kc < 2; ++kc) {
            const unsigned* p = pc + (size_t)arow*64 + 32*kc + 8*quad;
            rP[kc][0] = *(const uint4v*)p;
            rP[kc][1] = *(const uint4v*)(p + 4);
        }
#pragma unroll
        for (int ni = 0; ni < 4; ++ni)
            preV[ni] = *(const float4*)(vc + (size_t)(l15 + 16*ni)*64 + wr0);
    }
    __syncthreads();

    short8 aH[2], aL[2];
#pragma unroll
    for (int kc = 0; kc < 2; ++kc) unpack_frag(rP[kc][0], rP[kc][1], aH[kc], aL[kc]);

    int cur = 0;
    for (int i = 1; i < 8; ++i) {
        const int idx = base + i * estride;
        floatx4 accP[4], accV[4];
#pragma unroll
        for (int ni = 0; ni < 4; ++ni) {
            accV[ni][0] = preV[ni].x; accV[ni][1] = preV[ni].y;
            accV[ni][2] = preV[ni].z; accV[ni][3] = preV[ni].w;
            accP[ni][0]=accP[ni][1]=accP[ni][2]=accP[ni][3]=0.0f;
        }
        if (i + 1 < 8) {
            const unsigned* pc = P32 + (size_t)(base + (i+1) * estride) * 4096;
            const float*    vc = VT  + (size_t)(base + (i+1) * estride) * 4096;
#pragma unroll
            for (int kc = 0; kc < 2; ++kc) {
                const unsigned* p = pc + (size_t)arow*64 + 32*kc + 8*quad;
                rP[kc][0] = *(const uint4v*)p;
                rP[kc][1] = *(const uint4v*)(p + 4);
            }
#pragma unroll
            for (int ni = 0; ni < 4; ++ni)
                preV[ni] = *(const float4*)(vc + (size_t)(l15 + 16*ni)*64 + wr0);
        }
#pragma unroll
        for (int kc = 0; kc < 2; ++kc) {
            const int ko = 32*kc + 8*quad;
#pragma unroll
            for (int ni = 0; ni < 4; ++ni) {
                const int n = l15 + 16*ni;
                short8 pH = *(const short8*)&PBh[cur][n][ko];
                short8 pL = *(const short8*)&PBl[cur][n][ko];
                short8 vH = *(const short8*)&VBh[cur][n][ko];
                short8 vL = *(const short8*)&VBl[cur][n][ko];
                accP[ni] = mfma_bf16(aH[kc], pH, accP[ni]);
                accP[ni] = mfma_bf16(aH[kc], pL, accP[ni]);
                accP[ni] = mfma_bf16(aL[kc], pH, accP[ni]);
                accV[ni] = mfma_bf16(aH[kc], vH, accV[ni]);
                accV[ni] = mfma_bf16(aH[kc], vL, accV[ni]);
                accV[ni] = mfma_bf16(aL[kc], vH, accV[ni]);
            }
        }
        if (i + 1 < 8) {
#pragma unroll
            for (int kc = 0; kc < 2; ++kc) unpack_frag(rP[kc][0], rP[kc][1], aH[kc], aL[kc]);
        }
        unsigned* po = P32 + (size_t)idx * 4096;
        const int nb = cur ^ 1;
#pragma unroll
        for (int ni = 0; ni < 4; ++ni) {
            const int cc = l15 + 16*ni;
            *(floatx4*)(VT + (size_t)idx*4096 + cc*64 + wr0) = accV[ni];
            short4v h4, l4;
#pragma unroll
            for (int r = 0; r < 4; ++r) {
                short hh, ll; split_bf16(accP[ni][r], hh, ll);
                po[(size_t)(wr0+r)*64 + cc] = ((unsigned)(unsigned short)hh << 16) | (unsigned)(unsigned short)ll;
                h4[r]=hh; l4[r]=ll;
            }
            if (i + 1 < 8) {
                *(short4v*)&PBh[nb][cc][wr0] = h4; *(short4v*)&PBl[nb][cc][wr0] = l4;
                short4v vh4, vl4;
#pragma unroll
                for (int r = 0; r < 4; ++r) { short hh,ll; split_bf16(accV[ni][r],hh,ll); vh4[r]=hh; vl4[r]=ll; }
                *(short4v*)&VBh[nb][cc][wr0] = vh4; *(short4v*)&VBl[nb][cc][wr0] = vl4;
            }
        }
        if (i + 1 < 8) __syncthreads();
        cur ^= 1;
    }
}

// ---------------------------------------------------------------------------
// S3: 1 block. E_0 = 0; E_{s+1} = P[64s+63]*E_s + V[64s+63].
// P-frags per-wave from global; E dbuf in LDS; one barrier per iter.
// Stores E_{s+1} fp32 into dead P32 slot idx=64s+63, layout [b][n].
// ---------------------------------------------------------------------------
__global__ __launch_bounds__(256, 2)
void hippo_s3(unsigned* __restrict__ P32, const float* __restrict__ VT)
{
    __shared__ short EBh[2][NB][AS], EBl[2][NB][AS];
    const int tid = threadIdx.x;
    const int w = tid >> 6, lane = tid & 63, quad = lane >> 4, l15 = lane & 15;
    const int arow = 16*w + l15;
    const int wr0  = 16*w + 4*quad;

#pragma unroll
    for (int q = 0; q < 16; ++q) {
        int f = tid + q * 256; EBh[0][f >> 6][f & 63] = 0; EBl[0][f >> 6][f & 63] = 0;
    }
    uint4v rP[2][2]; float4 preV[4];
    {
        const unsigned* pc = P32 + (size_t)63 * 4096;
        const float*    vc = VT  + (size_t)63 * 4096;
#pragma unroll
        for (int kc = 0; kc < 2; ++kc) {
            const unsigned* p = pc + (size_t)arow*64 + 32*kc + 8*quad;
            rP[kc][0] = *(const uint4v*)p;
            rP[kc][1] = *(const uint4v*)(p + 4);
        }
#pragma unroll
        for (int ni = 0; ni < 4; ++ni)
            preV[ni] = *(const float4*)(vc + (size_t)(l15 + 16*ni)*64 + wr0);
    }
    __syncthreads();

    short8 aH[2], aL[2];
#pragma unroll
    for (int kc = 0; kc < 2; ++kc) unpack_frag(rP[kc][0], rP[kc][1], aH[kc], aL[kc]);

    int cur = 0;
    for (int s = 0; s < 7; ++s) {
        const int idx = 64 * s + 63;
        floatx4 acc[4];
#pragma unroll
        for (int ni = 0; ni < 4; ++ni) {
            acc[ni][0] = preV[ni].x; acc[ni][1] = preV[ni].y;
            acc[ni][2] = preV[ni].z; acc[ni][3] = preV[ni].w;
        }
        if (s + 1 < 7) {
            const int idx2 = 64 * (s + 1) + 63;
            const unsigned* pc = P32 + (size_t)idx2 * 4096;
            const float*    vc = VT  + (size_t)idx2 * 4096;
#pragma unroll
            for (int kc = 0; kc < 2; ++kc) {
                const unsigned* p = pc + (size_t)arow*64 + 32*kc + 8*quad;
                rP[kc][0] = *(const uint4v*)p;
                rP[kc][1] = *(const uint4v*)(p + 4);
            }
#pragma unroll
            for (int ni = 0; ni < 4; ++ni)
                preV[ni] = *(const float4*)(vc + (size_t)(l15 + 16*ni)*64 + wr0);
        }
#pragma unroll
        for (int kc = 0; kc < 2; ++kc) {
            const int ko = 32*kc + 8*quad;
#pragma unroll
            for (int ni = 0; ni < 4; ++ni) {
                const int n = l15 + 16*ni;
                short8 eH = *(const short8*)&EBh[cur][n][ko];
                short8 eL = *(const short8*)&EBl[cur][n][ko];
                acc[ni] = mfma_bf16(aH[kc], eH, acc[ni]);
                acc[ni] = mfma_bf16(aH[kc], eL, acc[ni]);
                acc[ni] = mfma_bf16(aL[kc], eH, acc[ni]);
            }
        }
        if (s + 1 < 7) {
#pragma unroll
            for (int kc = 0; kc < 2; ++kc) unpack_frag(rP[kc][0], rP[kc][1], aH[kc], aL[kc]);
        }
        float* eo = (float*)(P32 + (size_t)idx * 4096);
        const int nb = cur ^ 1;
#pragma unroll
        for (int ni = 0; ni < 4; ++ni) {
            const int cc = l15 + 16*ni;
            *(floatx4*)(eo + cc*64 + wr0) = acc[ni];
            if (s + 1 < 7) {
                short4v h4, l4;
#pragma unroll
                for (int r = 0; r < 4; ++r) { short hh,ll; split_bf16(acc[ni][r],hh,ll); h4[r]=hh; l4[r]=ll; }
                *(short4v*)&EBh[nb][cc][wr0] = h4; *(short4v*)&EBl[nb][cc][wr0] = l4;
            }
        }
        if (s + 1 < 7) __syncthreads();
        cur ^= 1;
    }
}

// ---------------------------------------------------------------------------
// Phase 3: entering state = (super E) combined with stored prefixes, then
// x <- A[t] x + u_t for 8 local steps.  A/P frags per-wave from global;
// X dbuf in LDS; one barrier per step/combine.
// ---------------------------------------------------------------------------
__global__ __launch_bounds__(256, 2)
void hippo_phase3(const float* __restrict__ inp, const float* __restrict__ Ag,
                  const float* __restrict__ Bst, const unsigned* __restrict__ P32,
                  const float* __restrict__ VT, float* __restrict__ out)
{
    __shared__ short XBh[2][NB][AS], XBl[2][NB][AS];

    const int tid = threadIdx.x, c = blockIdx.x, t0 = c * CH;
    const int w = tid >> 6, lane = tid & 63, quad = lane >> 4, l15 = lane & 15;
    const int arow = 16*w + l15;
    const int wr0  = 16*w + 4*quad;
    const int sup = c >> 6, g = c >> 3, gi = g & 7, j = c & 7;

    // issue A[t0] frag loads + b/i(t0) early (hide HBM under combines)
    float4 rA[2][2];
#pragma unroll
    for (int kc = 0; kc < 2; ++kc) {
        const float* p = Ag + (size_t)t0*4096 + (size_t)arow*64 + 32*kc + 8*quad;
        rA[kc][0] = *(const float4*)p;
        rA[kc][1] = *(const float4*)(p + 4);
    }
    float4 bcur = *(const float4*)(Bst + (size_t)t0*64 + wr0);
    float icur[4];
#pragma unroll
    for (int ni = 0; ni < 4; ++ni) icur[ni] = inp[(size_t)t0*64 + l15 + 16*ni];

    // ---- entering super state -> buf 0 ----
    if (sup == 0) {
#pragma unroll
        for (int q = 0; q < 16; ++q) { int f = tid + q*256; XBh[0][f>>6][f&63] = 0; XBl[0][f>>6][f&63] = 0; }
    } else {
        const float* e = (const float*)(P32 + (size_t)(64*(sup-1) + 63) * 4096);  // E_sup [b][n]
#pragma unroll
        for (int q = 0; q < 4; ++q) {
            int f = tid + q*256; int b = f>>4, k0 = (f&15)*4;
            float4 v = *(const float4*)(e + b*64 + k0);
            float va[4] = {v.x,v.y,v.z,v.w};
            short4v h4, l4;
#pragma unroll
            for (int r=0;r<4;++r){short hh,ll;split_bf16(va[r],hh,ll);h4[r]=hh;l4[r]=ll;}
            *(short4v*)&XBh[0][b][k0] = h4; *(short4v*)&XBl[0][b][k0] = l4;
        }
    }
    __syncthreads();
    int cur = 0;

    // ---- apply stored prefixes: X <- P[idx]*X + V[idx] ----
    auto combine = [&](int idx) {
        uint4v rP[2][2];
        const unsigned* pc = P32 + (size_t)idx * 4096;
        const float*    vc = VT  + (size_t)idx * 4096;
#pragma unroll
        for (int kc = 0; kc < 2; ++kc) {
            const unsigned* p = pc + (size_t)arow*64 + 32*kc + 8*quad;
            rP[kc][0] = *(const uint4v*)p;
            rP[kc][1] = *(const uint4v*)(p + 4);
        }
        floatx4 acc[4];
#pragma unroll
        for (int ni = 0; ni < 4; ++ni) {
            float4 vv = *(const float4*)(vc + (size_t)(l15 + 16*ni)*64 + wr0);
            acc[ni][0]=vv.x; acc[ni][1]=vv.y; acc[ni][2]=vv.z; acc[ni][3]=vv.w;
        }
        short8 cH[2], cL[2];
#pragma unroll
        for (int kc = 0; kc < 2; ++kc) unpack_frag(rP[kc][0], rP[kc][1], cH[kc], cL[kc]);
#pragma unroll
        for (int kc = 0; kc < 2; ++kc) {
            const int ko = 32*kc + 8*quad;
#pragma unroll
            for (int ni = 0; ni < 4; ++ni) {
                const int n = l15 + 16*ni;
                short8 xH = *(const short8*)&XBh[cur][n][ko];
                short8 xL = *(const short8*)&XBl[cur][n][ko];
                acc[ni] = mfma_bf16(cH[kc], xH, acc[ni]);
                acc[ni] = mfma_bf16(cH[kc], xL, acc[ni]);
                acc[ni] = mfma_bf16(cL[kc], xH, acc[ni]);
            }
        }
        const int nb = cur ^ 1;
#pragma unroll
        for (int ni = 0; ni < 4; ++ni) {
            const int cc = l15 + 16*ni;
            short4v h4, l4;
#pragma unroll
            for (int r=0;r<4;++r){short hh,ll;split_bf16(acc[ni][r],hh,ll);h4[r]=hh;l4[r]=ll;}
            *(short4v*)&XBh[nb][cc][wr0] = h4; *(short4v*)&XBl[nb][cc][wr0] = l4;
        }
        __syncthreads();
        cur ^= 1;
    };
    if (gi) combine(8*g - 1);   // in-super group prefix (S2 output)
    if (j)  combine(c - 1);     // in-group chunk prefix (S1 output)

    // convert A[t0] frags (loads issued at kernel start)
    short8 aH[2], aL[2];
#pragma unroll
    for (int kc = 0; kc < 2; ++kc) cvt_frag(rA[kc][0], rA[kc][1], aH[kc], aL[kc]);

    // ---- 8 local time steps ----
    float4 bnxt; float inxt[4];
    floatx4 acc[4];
    for (int s = 0; s < CH; ++s) {
        const int t = t0 + s;
        if (s + 1 < CH) {
            const int t1 = t + 1;
#pragma unroll
            for (int kc = 0; kc < 2; ++kc) {
                const float* p = Ag + (size_t)t1*4096 + (size_t)arow*64 + 32*kc + 8*quad;
                rA[kc][0] = *(const float4*)p;
                rA[kc][1] = *(const float4*)(p + 4);
            }
            bnxt = *(const float4*)(Bst + (size_t)t1*64 + wr0);
#pragma unroll
            for (int ni = 0; ni < 4; ++ni) inxt[ni] = inp[(size_t)t1*64 + l15 + 16*ni];
        }
        {
            float bc[4] = {bcur.x,bcur.y,bcur.z,bcur.w};
#pragma unroll
            for (int ni=0;ni<4;++ni)
#pragma unroll
            for (int r=0;r<4;++r) acc[ni][r] = bc[r] * icur[ni];
        }
#pragma unroll
        for (int kc = 0; kc < 2; ++kc) {
            const int ko = 32*kc + 8*quad;
#pragma unroll
            for (int ni = 0; ni < 4; ++ni) {
                const int n = l15 + 16*ni;
                short8 xH = *(const short8*)&XBh[cur][n][ko];
                short8 xL = *(const short8*)&XBl[cur][n][ko];
                acc[ni] = mfma_bf16(aH[kc], xH, acc[ni]);
                acc[ni] = mfma_bf16(aH[kc], xL, acc[ni]);
                acc[ni] = mfma_bf16(aL[kc], xH, acc[ni]);
            }
        }
        if (s + 1 < CH) {
#pragma unroll
            for (int kc = 0; kc < 2; ++kc) cvt_frag(rA[kc][0], rA[kc][1], aH[kc], aL[kc]);
        }
        const int nb = cur ^ 1;
#pragma unroll
        for (int ni = 0; ni < 4; ++ni) {
            const int cc = l15 + 16*ni;
            *(floatx4*)(out + (size_t)t*4096 + cc*64 + wr0) = acc[ni];   // out[t][b][n0..3]
            if (s + 1 < CH) {
                short4v h4, l4;
#pragma unroll
                for (int r=0;r<4;++r){short hh,ll;split_bf16(acc[ni][r],hh,ll);h4[r]=hh;l4[r]=ll;}
                *(short4v*)&XBh[nb][cc][wr0] = h4; *(short4v*)&XBl[nb][cc][wr0] = l4;
            }
        }
        if (s + 1 < CH) { __syncthreads(); cur ^= 1; }
        bcur = bnxt;
#pragma unroll
        for (int ni = 0; ni < 4; ++ni) icur[ni] = inxt[ni];
    }
}

extern "C" void kernel_launch(void* const* d_in, const int* in_sizes, int n_in,
                              void* d_out, int out_size, void* d_ws, size_t ws_size,
                              hipStream_t stream)
{
    const float* inp = (const float*)d_in[0];   // (L, B)
    const float* A   = (const float*)d_in[1];   // (L, N, N)
    const float* Bst = (const float*)d_in[2];   // (L, N)
    float* out = (float*)d_out;                  // (L, B, N)
    float* ws  = (float*)d_ws;                   // 16 MB used

    unsigned* P32 = (unsigned*)ws;               // 8 MB: packed hi|lo, row-major
    float*    VT  = ws + (size_t)CN * 4096;      // 8 MB: fp32, transposed

    hippo_phase1<<<CN, 256, 0, stream>>>(inp, A, Bst, P32, VT);
    hippo_seqscan<<<64, 256, 0, stream>>>(P32, VT, 8, 0, 1);
    hippo_seqscan<<<8, 256, 0, stream>>>(P32, VT, 64, 7, 8);
    hippo_s3<<<1, 256, 0, stream>>>(P32, VT);
    hippo_phase3<<<CN, 256, 0, stream>>>(inp, A, Bst, P32, VT, out);
}